// Round 1
// baseline (688.778 us; speedup 1.0000x reference)
//
#include <hip/hip_runtime.h>

// LIF neuron scan, decoupled two-pass.
// x: [T=500, B=1024, N=256] f32, w: [256] f32
// out: v_seq [T,B] then z_seq [T,B], f32.
//
// Insight: p[t,b] = x[t,b,:].w is independent of the recurrence; only the
// 2-FLOP v/z update is sequential. The previous fused kernel bound the whole
// 524 MB stream to 1024 waves (1 wave/SIMD, 10% occupancy) and exposed the
// shfl-reduce DS chain per step. Split instead:
//   Pass 1: full-occupancy streaming matvec -> p [T,B] (2 MB, workspace).
//   Pass 2: 1024-thread scan over p with a deep register prefetch ring.

#define T_STEPS 500
#define BATCH   1024
#define NDIM    256
#define ALPHA_F 0.995f
#define ROWS    (T_STEPS * BATCH)      // 512000 dot-product rows
#define NGROUPS (ROWS / 4)             // 128000 groups of 4 contiguous rows

// ---------------------------------------------------------------------------
// Pass 1: p[r] = dot(x[r,:], w).  Wave-per-4-rows (4 KB contiguous per
// iteration), grid-stride over 8192 waves (2048 blocks = 8 blocks/CU, full
// 32-wave occupancy). Memory-bound: 524 MB read.
__global__ __launch_bounds__(256) void lif_matvec_kernel(
    const float* __restrict__ x, const float* __restrict__ w,
    float* __restrict__ p)
{
    const int lane = threadIdx.x & 63;
    const int wid  = (int)((blockIdx.x * blockDim.x + threadIdx.x) >> 6);
    const int nw   = (int)((gridDim.x * blockDim.x) >> 6);

    const float4 wv = *(const float4*)(w + lane * 4);

    for (int g = wid; g < NGROUPS; g += nw) {
        const float* xr = x + (size_t)g * (4 * NDIM) + lane * 4;
        const float4 a0 = *(const float4*)(xr);
        const float4 a1 = *(const float4*)(xr + NDIM);
        const float4 a2 = *(const float4*)(xr + 2 * NDIM);
        const float4 a3 = *(const float4*)(xr + 3 * NDIM);

        float s0 = a0.x * wv.x + a0.y * wv.y + a0.z * wv.z + a0.w * wv.w;
        float s1 = a1.x * wv.x + a1.y * wv.y + a1.z * wv.z + a1.w * wv.w;
        float s2 = a2.x * wv.x + a2.y * wv.y + a2.z * wv.z + a2.w * wv.w;
        float s3 = a3.x * wv.x + a3.y * wv.y + a3.z * wv.z + a3.w * wv.w;

#pragma unroll
        for (int m = 32; m >= 1; m >>= 1) {
            s0 += __shfl_xor(s0, m, 64);
            s1 += __shfl_xor(s1, m, 64);
            s2 += __shfl_xor(s2, m, 64);
            s3 += __shfl_xor(s3, m, 64);
        }

        if (lane == 0)
            *(float4*)(p + (size_t)g * 4) = make_float4(s0, s1, s2, s3);
    }
}

// ---------------------------------------------------------------------------
// Pass 2: sequential LIF recurrence per batch column. 1024 threads (4 blocks).
// p is 2 MB -> L2/L3 resident; 25-deep register ring hides read latency
// (500 = 25 * 20, all ring indices compile-time constant -> stays in VGPRs).
// NOTE: no __restrict__ here — p may alias vout (fallback when ws too small);
// thread c reads p[(t+25)*B+c] before it ever writes vout[t*B+c], and each
// column is touched by exactly one thread, so the aliasing is benign.
#define DEPTH2 25

__global__ __launch_bounds__(256) void lif_scan_kernel(
    const float* p, float* vout, float* zout)
{
    const int c = blockIdx.x * 256 + threadIdx.x;   // 0..1023

    float v = 0.0f, z = 0.0f;
    float buf[DEPTH2];
#pragma unroll
    for (int j = 0; j < DEPTH2; ++j)
        buf[j] = p[(size_t)j * BATCH + c];

    // main: t = 0..474, prefetch t+25 (<= 499) into the vacated slot
    for (int t0 = 0; t0 < T_STEPS - DEPTH2; t0 += DEPTH2) {
#pragma unroll
        for (int j = 0; j < DEPTH2; ++j) {
            const int t = t0 + j;
            const float pt = buf[j];
            buf[j] = p[(size_t)(t + DEPTH2) * BATCH + c];
            v = ALPHA_F * v + pt - z;               // v_th = 1
            z = (v - 1.0f > 0.0f) ? 1.0f : 0.0f;
            vout[(size_t)t * BATCH + c] = v;
            zout[(size_t)t * BATCH + c] = z;
        }
    }

    // epilogue: t = 475..499 from the ring
#pragma unroll
    for (int j = 0; j < DEPTH2; ++j) {
        const int t = T_STEPS - DEPTH2 + j;
        const float pt = buf[j];
        v = ALPHA_F * v + pt - z;
        z = (v - 1.0f > 0.0f) ? 1.0f : 0.0f;
        vout[(size_t)t * BATCH + c] = v;
        zout[(size_t)t * BATCH + c] = z;
    }
}

// ---------------------------------------------------------------------------
extern "C" void kernel_launch(void* const* d_in, const int* in_sizes, int n_in,
                              void* d_out, int out_size, void* d_ws, size_t ws_size,
                              hipStream_t stream)
{
    const float* x = (const float*)d_in[0];   // [T, B, N] f32
    const float* w = (const float*)d_in[1];   // [N] f32
    float* out  = (float*)d_out;
    float* vout = out;                                   // v_seq [T,B]
    float* zout = out + (size_t)T_STEPS * BATCH;         // z_seq [T,B]

    // p [T,B] = 2 MB. Prefer workspace; fall back to staging inside vout
    // (exactly [T,B] f32 — scan reads ahead of its in-place overwrite).
    float* p = (ws_size >= (size_t)ROWS * sizeof(float)) ? (float*)d_ws : vout;

    lif_matvec_kernel<<<2048, 256, 0, stream>>>(x, w, p);
    lif_scan_kernel<<<BATCH / 256, 256, 0, stream>>>(p, vout, zout);
}